// Round 11
// baseline (1651.565 us; speedup 1.0000x reference)
//
#include <hip/hip_runtime.h>
#include <hip/hip_bf16.h>

#define NN 50000
#define DM 128
#define EE 800000
#define NH 4
#define HDIM 512      // NH * DM
#define NRELS 64
#define RDIM 64
#define LAYERS 2
#define NB 196        // ceil(NN/256)

// prep_misc block ranges
#define PM_HB 6250    // NN*DM/4/256
#define PM_WC 1024    // 4*DM*HDIM/256
#define PM_XE 256     // LAYERS*NRELS*HDIM/256
#define PM_CZ 196     // NB
#define PM_TOT (PM_HB + PM_WC + PM_XE + PM_CZ + 1)

typedef short frag8 __attribute__((ext_vector_type(8)));   // 8 bf16 (bits)
typedef float f32x4 __attribute__((ext_vector_type(4)));
typedef float f32x2 __attribute__((ext_vector_type(2)));

__device__ __forceinline__ float b2f(unsigned short u) {
    unsigned v = ((unsigned)u) << 16;
    union { unsigned u; float f; } c; c.u = v; return c.f;
}
__device__ __forceinline__ float b2f_lo(unsigned u) {
    union { unsigned u; float f; } c; c.u = u << 16; return c.f;
}
__device__ __forceinline__ float b2f_hi(unsigned u) {
    union { unsigned u; float f; } c; c.u = u & 0xFFFF0000u; return c.f;
}
// raw hi: skip the mask; low-16 garbage adds <=2^-7 relative (~bf16 rounding scale)
__device__ __forceinline__ float b2f_hi_raw(unsigned u) {
    union { unsigned u; float f; } c; c.u = u; return c.f;
}
__device__ __forceinline__ unsigned short f2b(float f) {
    union { float f; unsigned u; } c; c.f = f;
    unsigned u = c.u;
    u += 0x7FFFu + ((u >> 16) & 1u);   // round-to-nearest-even
    return (unsigned short)(u >> 16);
}

// DPP 16-lane row sum-reduce step (pure VALU, no DS)
template<int CTRL>
__device__ __forceinline__ float dpp_add(float x) {
    int yi = __builtin_amdgcn_update_dpp(0, __builtin_bit_cast(int, x),
                                         CTRL, 0xF, 0xF, true);
    return x + __builtin_bit_cast(float, yi);
}

// ---------------- CSR build ----------------
__global__ void count_kernel(const int* __restrict__ dst, int* __restrict__ counts) {
    int e = blockIdx.x * 256 + threadIdx.x;
    if (e < EE) atomicAdd(&counts[dst[e]], 1);
}

__global__ __launch_bounds__(256) void psum_kernel(const int* __restrict__ counts,
                                                   int* __restrict__ psums) {
    int idx = blockIdx.x * 256 + threadIdx.x;
    int x = (idx < NN) ? counts[idx] : 0;
    int lane = threadIdx.x & 63, wv = threadIdx.x >> 6;
    #pragma unroll
    for (int d = 1; d < 64; d <<= 1) x += __shfl_xor(x, d, 64);
    __shared__ int ws[4];
    if (lane == 0) ws[wv] = x;
    __syncthreads();
    if (threadIdx.x == 0) psums[blockIdx.x] = ws[0] + ws[1] + ws[2] + ws[3];
}

__global__ __launch_bounds__(256) void pscan_kernel(const int* __restrict__ psums,
                                                    int* __restrict__ offs,
                                                    int* __restrict__ row_ptr) {
    int t = threadIdx.x;
    int x = (t < NB) ? psums[t] : 0;
    int lane = t & 63, wv = t >> 6;
    int incl = x;
    #pragma unroll
    for (int d = 1; d < 64; d <<= 1) {
        int y = __shfl_up(incl, d, 64);
        if (lane >= d) incl += y;
    }
    __shared__ int ws[4];
    if (lane == 63) ws[wv] = incl;
    __syncthreads();
    int off = 0;
    for (int k = 0; k < wv; ++k) off += ws[k];
    if (t < NB) offs[t] = incl + off - x;   // exclusive
    if (t == 0) row_ptr[0] = 0;
}

__global__ __launch_bounds__(256) void pfin_kernel(const int* __restrict__ counts,
                                                   const int* __restrict__ offs,
                                                   int* __restrict__ row_ptr,
                                                   int* __restrict__ cursor) {
    int idx = blockIdx.x * 256 + threadIdx.x;
    int x = (idx < NN) ? counts[idx] : 0;
    int lane = threadIdx.x & 63, wv = threadIdx.x >> 6;
    int incl = x;
    #pragma unroll
    for (int d = 1; d < 64; d <<= 1) {
        int y = __shfl_up(incl, d, 64);
        if (lane >= d) incl += y;
    }
    __shared__ int ws[4];
    if (lane == 63) ws[wv] = incl;
    __syncthreads();
    int off = offs[blockIdx.x];
    for (int k = 0; k < wv; ++k) off += ws[k];
    if (idx < NN) {
        int v = off + incl;
        row_ptr[idx + 1] = v;
        cursor[idx] = v - x;
    }
}

// scatter + pkq build (layer-invariant): pkq[p] = {src<<10, rel<<10} byte offsets, CSR order
__global__ void scatter_pk_kernel(const int* __restrict__ ei, const int* __restrict__ etype,
                                  int* __restrict__ cursor, uint2* __restrict__ pkq) {
    int e = blockIdx.x * 256 + threadIdx.x;
    if (e < EE) {
        int d = ei[EE + e];
        int p = atomicAdd(&cursor[d], 1);
        uint2 v;
        v.x = (unsigned)ei[e] << 10;
        v.y = (unsigned)etype[e] << 10;
        pkq[p] = v;
    }
}

// ---------------- fused prep: hb, wconv, xe(bf16), counts=0, be, ctr=0 ----------------
__global__ __launch_bounds__(256) void prep_misc_kernel(
    const float* __restrict__ x_flat,
    const float* __restrict__ Wl, const float* __restrict__ Wr,
    const float* __restrict__ rel_emb, const float* __restrict__ We,
    const float* __restrict__ att,
    unsigned short* __restrict__ hb, unsigned short* __restrict__ Wt,
    unsigned short* __restrict__ xeb, float* __restrict__ be,
    int* __restrict__ counts, int* __restrict__ ctr) {
    int b = blockIdx.x, t = threadIdx.x;
    if (b < PM_HB) {
        int idx = b * 256 + t;                      // < NN*DM/4
        float4 v = ((const float4*)x_flat)[idx];
        ushort4 o;
        o.x = f2b(v.x); o.y = f2b(v.y); o.z = f2b(v.z); o.w = f2b(v.w);
        ((ushort4*)hb)[idx] = o;
        return;
    }
    b -= PM_HB;
    if (b < PM_WC) {
        int idx = b * 256 + t;                      // < 4*DM*HDIM
        int m = idx >> 16;
        int r = idx & 65535;
        int c = r >> 7, k = r & 127;
        int l = m >> 1;
        const float* W = (m & 1) ? Wr : Wl;
        Wt[idx] = f2b(W[(size_t)l * DM * HDIM + k * HDIM + c]);
        return;
    }
    b -= PM_WC;
    if (b < PM_XE) {
        int idx = b * 256 + t;                      // < LAYERS*NRELS*HDIM
        int l  = idx / (NRELS * HDIM);
        int r  = (idx / HDIM) & (NRELS - 1);
        int hc = idx & (HDIM - 1);
        const float* Wel = We + (size_t)l * RDIM * HDIM;
        float s = 0.f;
        #pragma unroll 8
        for (int d = 0; d < RDIM; ++d) s += rel_emb[r * RDIM + d] * Wel[d * HDIM + hc];
        xeb[idx] = f2b(s);
        return;
    }
    b -= PM_XE;
    if (b < PM_CZ) {
        int idx = b * 256 + t;
        if (idx < NN) counts[idx] = 0;
        return;
    }
    // be block (+ persistent-wave counters)
    if (t < 2) ctr[t] = 0;
    __shared__ float aw_s[LAYERS * NH * RDIM];      // 512
    #pragma unroll
    for (int k = 0; k < 2; ++k) {
        int idx = t * 2 + k;                        // < 512
        int l = idx >> 8, h = (idx >> 6) & 3, d = idx & 63;
        const float* ap = att + (size_t)l * HDIM + h * DM;
        const float* wp = We + (size_t)l * RDIM * HDIM + (size_t)d * HDIM + h * DM;
        float s = 0.f;
        #pragma unroll 8
        for (int c = 0; c < DM; ++c) s += ap[c] * wp[c];
        aw_s[idx] = s;
    }
    __syncthreads();
    #pragma unroll
    for (int k = 0; k < 2; ++k) {
        int idx = t * 2 + k;                        // < 512 = L*NRELS*NH
        int l = idx >> 8, r = (idx >> 2) & 63, h = idx & 3;
        const float* rp = rel_emb + r * RDIM;
        const float* ap = aw_s + l * 256 + h * 64;
        float s = 0.f;
        #pragma unroll 8
        for (int d = 0; d < RDIM; ++d) s += rp[d] * ap[d];
        be[idx] = 0.6f * s;
    }
}

// ---------------- GEMM (M=32 tile, R8 known-good) + fused ab ----------------
__global__ __launch_bounds__(256) void gemm_xlxr_ab_kernel(
    const unsigned short* __restrict__ hb,        // [NN,128] bf16
    const unsigned short* __restrict__ WtL,       // [512][128] bf16 (transposed)
    const unsigned short* __restrict__ WtR,
    const float* __restrict__ bl, const float* __restrict__ br,
    const float* __restrict__ att_l,              // [512]
    unsigned short* __restrict__ xl, unsigned short* __restrict__ xr,
    float* __restrict__ ab) {
    int w = threadIdx.x >> 6, lane = threadIdx.x & 63;   // wave w owns head w
    int m0 = blockIdx.x * 32;
    int colL = lane & 15, kg = lane >> 4;

    frag8 a[2][4];
    #pragma unroll
    for (int mt = 0; mt < 2; ++mt) {
        int row = m0 + mt * 16 + colL;
        if (row >= NN) row = NN - 1;
        const unsigned short* arow = hb + (size_t)row * DM;
        #pragma unroll
        for (int kc = 0; kc < 4; ++kc) {
            uint4 raw = *(const uint4*)(arow + kc * 32 + kg * 8);
            a[mt][kc] = __builtin_bit_cast(frag8, raw);
        }
    }

    float prow[2][2][4];   // [mt][mat][r]
    #pragma unroll
    for (int mt = 0; mt < 2; ++mt)
        #pragma unroll
        for (int mat = 0; mat < 2; ++mat)
            #pragma unroll
            for (int r = 0; r < 4; ++r) prow[mt][mat][r] = 0.f;

    #pragma unroll
    for (int mat = 0; mat < 2; ++mat) {
        const unsigned short* Wt = mat ? WtR : WtL;
        const float* bias = mat ? br : bl;
        unsigned short* out = mat ? xr : xl;
        #pragma unroll
        for (int nt = 0; nt < 8; ++nt) {
            int col = w * 128 + nt * 16 + colL;
            f32x4 acc0 = {0.f, 0.f, 0.f, 0.f};
            f32x4 acc1 = {0.f, 0.f, 0.f, 0.f};
            #pragma unroll
            for (int kc = 0; kc < 4; ++kc) {
                uint4 raw = *(const uint4*)(Wt + (size_t)col * DM + kc * 32 + kg * 8);
                frag8 b = __builtin_bit_cast(frag8, raw);
                acc0 = __builtin_amdgcn_mfma_f32_16x16x32_bf16(a[0][kc], b, acc0, 0, 0, 0);
                acc1 = __builtin_amdgcn_mfma_f32_16x16x32_bf16(a[1][kc], b, acc1, 0, 0, 0);
            }
            float bb = bias[col];
            float ac = att_l[col];
            #pragma unroll
            for (int r = 0; r < 4; ++r) {
                float v0 = acc0[r] + bb;
                float v1 = acc1[r] + bb;
                int row0 = m0 + kg * 4 + r;
                int row1 = row0 + 16;
                if (row0 < NN) out[(size_t)row0 * HDIM + col] = f2b(v0);
                if (row1 < NN) out[(size_t)row1 * HDIM + col] = f2b(v1);
                prow[0][mat][r] = fmaf(ac, v0, prow[0][mat][r]);
                prow[1][mat][r] = fmaf(ac, v1, prow[1][mat][r]);
            }
        }
    }
    #pragma unroll
    for (int d = 1; d < 16; d <<= 1) {
        #pragma unroll
        for (int mt = 0; mt < 2; ++mt)
            #pragma unroll
            for (int mat = 0; mat < 2; ++mat)
                #pragma unroll
                for (int r = 0; r < 4; ++r)
                    prow[mt][mat][r] += __shfl_xor(prow[mt][mat][r], d, 64);
    }
    if (colL == 0) {
        #pragma unroll
        for (int mt = 0; mt < 2; ++mt) {
            int row = m0 + mt * 16 + kg * 4;
            #pragma unroll
            for (int mat = 0; mat < 2; ++mat)
                #pragma unroll
                for (int r = 0; r < 4; ++r)
                    if (row + r < NN)
                        ab[(size_t)(row + r) * 8 + mat * 4 + w] = 0.6f * prow[mt][mat][r];
        }
    }
}

// ------- fused per-node: PERSISTENT waves, dynamic node grab, 2-deep pipeline -------
__global__ __launch_bounds__(256) void node_fused_kernel(
    const int* __restrict__ row_ptr,
    const uint2* __restrict__ pkq,           // [EE] {src<<10, rel<<10}, CSR order
    const unsigned short* __restrict__ xl,   // [NN][512] bf16
    const unsigned short* __restrict__ xr,   // [NN][512] bf16
    const unsigned short* __restrict__ xeb_l,// [64][512] bf16 (this layer)
    const float* __restrict__ ab,            // [NN][8] f32 (dst part at +4)
    const float* __restrict__ be_l,          // [64][4] f32 (this layer)
    const float* __restrict__ att_l,         // [512] (this layer)
    const float* __restrict__ h_in,          // [NN][128]
    const float* __restrict__ b_out, const float* __restrict__ ln_g,
    const float* __restrict__ ln_b,
    float* __restrict__ h_out,
    unsigned short* __restrict__ hb_out,
    int* __restrict__ ctr) {
    int w = threadIdx.x >> 6, l = threadIdx.x & 63;
    int hh = l >> 4;
    __shared__ float cl[4][64][4];
    __shared__ uint2 pk_s[4][64];

    int c0 = (l & 15) * 8;

    // node-invariant loads (hoisted)
    float4 at0 = ((const float4*)(att_l + l * 8))[0];
    float4 at1 = ((const float4*)(att_l + l * 8))[1];
    float atv[8] = {at0.x * 0.4f, at0.y * 0.4f, at0.z * 0.4f, at0.w * 0.4f,
                    at1.x * 0.4f, at1.y * 0.4f, at1.z * 0.4f, at1.w * 0.4f};
    float4 bo0 = *(const float4*)(b_out + c0);
    float4 bo1 = *(const float4*)(b_out + c0 + 4);
    float bov[8] = {bo0.x, bo0.y, bo0.z, bo0.w, bo1.x, bo1.y, bo1.z, bo1.w};
    float4 g0 = *(const float4*)(ln_g + c0);
    float4 g1 = *(const float4*)(ln_g + c0 + 4);
    float4 q0 = *(const float4*)(ln_b + c0);
    float4 q1 = *(const float4*)(ln_b + c0 + 4);

    const char* xl_b = (const char*)xl;
    const char* xe_b = (const char*)xeb_l;
    uint l16 = (uint)l << 4;

    for (;;) {
        int i = 0;
        if (l == 0) i = atomicAdd(ctr, 1);
        i = __shfl(i, 0, 64);
        if (i >= NN) break;

        int beg = row_ptr[i], end = row_ptr[i + 1];

        uint4 xrv = *(const uint4*)(xr + (size_t)i * HDIM + l * 8);
        f32x2 xrp0 = f32x2{b2f_lo(xrv.x), b2f_hi(xrv.x)};
        f32x2 xrp1 = f32x2{b2f_lo(xrv.y), b2f_hi(xrv.y)};
        f32x2 xrp2 = f32x2{b2f_lo(xrv.z), b2f_hi(xrv.z)};
        f32x2 xrp3 = f32x2{b2f_lo(xrv.w), b2f_hi(xrv.w)};
        float4 bxv = ((const float4*)ab)[2 * i + 1];   // 0.6 att.xr_i per head
        float4 hv0 = *(const float4*)(h_in + (size_t)i * DM + c0);
        float4 hv1 = *(const float4*)(h_in + (size_t)i * DM + c0 + 4);

        float ss = 0.f;
        f32x2 acc0 = f32x2{0.f, 0.f}, acc1 = f32x2{0.f, 0.f};
        f32x2 acc2 = f32x2{0.f, 0.f}, acc3 = f32x2{0.f, 0.f};

        for (int cb = beg; cb < end; cb += 64) {
            int mc = min(64, end - cb);
            if (l < mc) {
                uint2 pk = pkq[cb + l];
                pk_s[w][l] = pk;
                int s = pk.x >> 10, r = pk.y >> 10;
                float4 a4 = ((const float4*)ab)[2 * s];
                float4 b4 = ((const float4*)be_l)[r];
                cl[w][l][0] = a4.x + b4.x + bxv.x;
                cl[w][l][1] = a4.y + b4.y + bxv.y;
                cl[w][l][2] = a4.z + b4.z + bxv.z;
                cl[w][l][3] = a4.w + b4.w + bxv.w;
            }
            // 2-deep pipeline over edges (wave-synchronous, no barrier)
            uint2 pk0 = pk_s[w][0];
            uint4 vvP = *(const uint4*)(xl_b + pk0.x + l16);
            uint4 eeP = *(const uint4*)(xe_b + pk0.y + l16);
            float cjP = cl[w][0][hh];
            for (int j = 1; j <= mc; ++j) {
                uint4 vv = vvP; uint4 ee = eeP; float cj = cjP;
                if (j < mc) {
                    uint2 pkj = pk_s[w][j];
                    vvP = *(const uint4*)(xl_b + pkj.x + l16);
                    eeP = *(const uint4*)(xe_b + pkj.y + l16);
                    cjP = cl[w][j][hh];
                }
                f32x2 xp0 = f32x2{b2f_lo(vv.x), b2f_hi_raw(vv.x)};
                f32x2 xp1 = f32x2{b2f_lo(vv.y), b2f_hi_raw(vv.y)};
                f32x2 xp2 = f32x2{b2f_lo(vv.z), b2f_hi_raw(vv.z)};
                f32x2 xp3 = f32x2{b2f_lo(vv.w), b2f_hi_raw(vv.w)};
                f32x2 z0 = (xp0 + xrp0) + f32x2{b2f_lo(ee.x), b2f_hi_raw(ee.x)};
                f32x2 z1 = (xp1 + xrp1) + f32x2{b2f_lo(ee.y), b2f_hi_raw(ee.y)};
                f32x2 z2 = (xp2 + xrp2) + f32x2{b2f_lo(ee.z), b2f_hi_raw(ee.z)};
                f32x2 z3 = (xp3 + xrp3) + f32x2{b2f_lo(ee.w), b2f_hi_raw(ee.w)};
                float partial = fmaf(atv[0], fabsf(z0[0]),
                                fmaf(atv[1], fabsf(z0[1]),
                                fmaf(atv[2], fabsf(z1[0]),
                                fmaf(atv[3], fabsf(z1[1]),
                                fmaf(atv[4], fabsf(z2[0]),
                                fmaf(atv[5], fabsf(z2[1]),
                                fmaf(atv[6], fabsf(z3[0]), atv[7] * fabsf(z3[1]))))))));
                partial = dpp_add<0xB1>(partial);
                partial = dpp_add<0x4E>(partial);
                partial = dpp_add<0x124>(partial);
                partial = dpp_add<0x128>(partial);
                float we = __expf(partial + cj);
                ss += we;
                f32x2 wv = f32x2{we, we};
                acc0 += wv * xp0;
                acc1 += wv * xp1;
                acc2 += wv * xp2;
                acc3 += wv * xp3;
            }
        }

        // normalize per head, then sum across the 4 head groups (lanes ^16, ^32)
        float invs = (ss > 0.f) ? 1.f / ss : 0.f;
        float sv[8] = {acc0[0] * invs, acc0[1] * invs, acc1[0] * invs, acc1[1] * invs,
                       acc2[0] * invs, acc2[1] * invs, acc3[0] * invs, acc3[1] * invs};
        #pragma unroll
        for (int d = 16; d < 64; d <<= 1)
            #pragma unroll
            for (int k = 0; k < 8; ++k) sv[k] += __shfl_xor(sv[k], d, 64);

        float hvv[8] = {hv0.x, hv0.y, hv0.z, hv0.w, hv1.x, hv1.y, hv1.z, hv1.w};
        float yv[8];
        float la = 0.f, lb = 0.f;
        #pragma unroll
        for (int k = 0; k < 8; ++k) {
            float o = sv[k] * 0.25f + bov[k];
            float ge = 0.5f * o * (1.f + erff(o * 0.70710678118654752f));
            float y = hvv[k] + ge;
            yv[k] = y; la += y; lb += y * y;
        }
        la = dpp_add<0xB1>(la); la = dpp_add<0x4E>(la);
        la = dpp_add<0x124>(la); la = dpp_add<0x128>(la);
        lb = dpp_add<0xB1>(lb); lb = dpp_add<0x4E>(lb);
        lb = dpp_add<0x124>(lb); lb = dpp_add<0x128>(lb);
        float mean = la * (1.f / 128.f);
        float var = lb * (1.f / 128.f) - mean * mean;
        float rs = rsqrtf(var + 1e-5f);

        if (l < 16) {
            float gv[8] = {g0.x, g0.y, g0.z, g0.w, g1.x, g1.y, g1.z, g1.w};
            float qv[8] = {q0.x, q0.y, q0.z, q0.w, q1.x, q1.y, q1.z, q1.w};
            float ov[8];
            #pragma unroll
            for (int k = 0; k < 8; ++k)
                ov[k] = (yv[k] - mean) * rs * gv[k] + qv[k];
            float* hop = h_out + (size_t)i * DM + c0;
            *(float4*)hop = make_float4(ov[0], ov[1], ov[2], ov[3]);
            *(float4*)(hop + 4) = make_float4(ov[4], ov[5], ov[6], ov[7]);
            uint4 ob;
            ob.x = (unsigned)f2b(ov[0]) | ((unsigned)f2b(ov[1]) << 16);
            ob.y = (unsigned)f2b(ov[2]) | ((unsigned)f2b(ov[3]) << 16);
            ob.z = (unsigned)f2b(ov[4]) | ((unsigned)f2b(ov[5]) << 16);
            ob.w = (unsigned)f2b(ov[6]) | ((unsigned)f2b(ov[7]) << 16);
            *(uint4*)(hb_out + (size_t)i * DM + c0) = ob;
        }
    }
}

// ---------------- launch ----------------
extern "C" void kernel_launch(void* const* d_in, const int* in_sizes, int n_in,
                              void* d_out, int out_size, void* d_ws, size_t ws_size,
                              hipStream_t stream) {
    const float* x_flat   = (const float*)d_in[0];
    const int*   edge_idx = (const int*)d_in[1];
    const int*   edge_ty  = (const int*)d_in[2];
    const float* rel_emb  = (const float*)d_in[3];
    const float* Wl       = (const float*)d_in[4];
    const float* bl       = (const float*)d_in[5];
    const float* Wr       = (const float*)d_in[6];
    const float* br       = (const float*)d_in[7];
    const float* We       = (const float*)d_in[8];
    const float* att      = (const float*)d_in[9];
    const float* b_out    = (const float*)d_in[10];
    const float* ln_g     = (const float*)d_in[11];
    const float* ln_b     = (const float*)d_in[12];

    char* p = (char*)d_ws;
    auto carve = [&](size_t bytes) {
        void* r = (void*)p;
        p += (bytes + 255) & ~(size_t)255;
        return r;
    };
    unsigned short* xl     = (unsigned short*)carve((size_t)NN * HDIM * 2);
    unsigned short* xr     = (unsigned short*)carve((size_t)NN * HDIM * 2);
    float*          h1     = (float*)carve((size_t)NN * DM * 4);
    unsigned short* hb     = (unsigned short*)carve((size_t)NN * DM * 2);
    unsigned short* Wt     = (unsigned short*)carve((size_t)4 * DM * HDIM * 2);
    unsigned short* xeb    = (unsigned short*)carve((size_t)LAYERS * NRELS * HDIM * 2);
    float*          ab     = (float*)carve((size_t)NN * 8 * 4);
    float*          be     = (float*)carve((size_t)LAYERS * NRELS * NH * 4);
    int*            row_ptr= (int*)carve((size_t)(NN + 1) * 4);
    int*            counts = (int*)carve((size_t)NN * 4);
    int*            cursor = (int*)carve((size_t)NN * 4);
    int*            psums  = (int*)carve((size_t)NB * 4);
    int*            offs   = (int*)carve((size_t)NB * 4);
    uint2*          pkq    = (uint2*)carve((size_t)EE * 8);
    int*            ctr    = (int*)carve((size_t)2 * 4);

    const int* dst = edge_idx + EE;

    // fused prep (hb, Wt, xeb, be, counts=0, ctr=0)
    prep_misc_kernel<<<PM_TOT, 256, 0, stream>>>(
        x_flat, Wl, Wr, rel_emb, We, att, hb, Wt, xeb, be, counts, ctr);

    // CSR build (parallel scan) + pkq
    count_kernel<<<(EE + 255) / 256, 256, 0, stream>>>(dst, counts);
    psum_kernel<<<NB, 256, 0, stream>>>(counts, psums);
    pscan_kernel<<<1, 256, 0, stream>>>(psums, offs, row_ptr);
    pfin_kernel<<<NB, 256, 0, stream>>>(counts, offs, row_ptr, cursor);
    scatter_pk_kernel<<<(EE + 255) / 256, 256, 0, stream>>>(edge_idx, edge_ty, cursor, pkq);

    const float* h_cur = x_flat;
    for (int l = 0; l < LAYERS; ++l) {
        float* h_next = (l == LAYERS - 1) ? (float*)d_out : h1;
        gemm_xlxr_ab_kernel<<<(NN + 31) / 32, 256, 0, stream>>>(
            hb,
            Wt + (size_t)(l * 2 + 0) * DM * HDIM,
            Wt + (size_t)(l * 2 + 1) * DM * HDIM,
            bl + (size_t)l * HDIM, br + (size_t)l * HDIM,
            att + (size_t)l * HDIM,
            xl, xr, ab);
        node_fused_kernel<<<2048, 256, 0, stream>>>(
            row_ptr, pkq, xl, xr,
            xeb + (size_t)l * NRELS * HDIM,
            ab, be + (size_t)l * NRELS * NH,
            att + (size_t)l * HDIM,
            h_cur,
            b_out + (size_t)l * DM, ln_g + (size_t)l * DM, ln_b + (size_t)l * DM,
            h_next, hb, ctr + l);
        h_cur = h_next;
    }
}

// Round 12
// 592.968 us; speedup vs baseline: 2.7853x; 2.7853x over previous
//
#include <hip/hip_runtime.h>
#include <hip/hip_bf16.h>

#define NN 50000
#define DM 128
#define EE 800000
#define NH 4
#define HDIM 512      // NH * DM
#define NRELS 64
#define RDIM 64
#define LAYERS 2
#define NB 196        // ceil(NN/256)
#define NWAVES 8192   // 2048 blocks x 4 waves

// prep_misc block ranges
#define PM_HB 6250    // NN*DM/4/256
#define PM_WC 1024    // 4*DM*HDIM/256
#define PM_XE 256     // LAYERS*NRELS*HDIM/256
#define PM_CZ 196     // NB
#define PM_TOT (PM_HB + PM_WC + PM_XE + PM_CZ + 1)

typedef short frag8 __attribute__((ext_vector_type(8)));   // 8 bf16 (bits)
typedef float f32x4 __attribute__((ext_vector_type(4)));
typedef float f32x2 __attribute__((ext_vector_type(2)));

__device__ __forceinline__ float b2f(unsigned short u) {
    unsigned v = ((unsigned)u) << 16;
    union { unsigned u; float f; } c; c.u = v; return c.f;
}
__device__ __forceinline__ float b2f_lo(unsigned u) {
    union { unsigned u; float f; } c; c.u = u << 16; return c.f;
}
__device__ __forceinline__ float b2f_hi(unsigned u) {
    union { unsigned u; float f; } c; c.u = u & 0xFFFF0000u; return c.f;
}
// raw hi: skip the mask; low-16 garbage adds <=2^-7 relative (~bf16 rounding scale)
__device__ __forceinline__ float b2f_hi_raw(unsigned u) {
    union { unsigned u; float f; } c; c.u = u; return c.f;
}
__device__ __forceinline__ unsigned short f2b(float f) {
    union { float f; unsigned u; } c; c.f = f;
    unsigned u = c.u;
    u += 0x7FFFu + ((u >> 16) & 1u);   // round-to-nearest-even
    return (unsigned short)(u >> 16);
}

// DPP 16-lane row sum-reduce step (pure VALU, no DS)
template<int CTRL>
__device__ __forceinline__ float dpp_add(float x) {
    int yi = __builtin_amdgcn_update_dpp(0, __builtin_bit_cast(int, x),
                                         CTRL, 0xF, 0xF, true);
    return x + __builtin_bit_cast(float, yi);
}

// ---------------- CSR build ----------------
__global__ void count_kernel(const int* __restrict__ dst, int* __restrict__ counts) {
    int e = blockIdx.x * 256 + threadIdx.x;
    if (e < EE) atomicAdd(&counts[dst[e]], 1);
}

__global__ __launch_bounds__(256) void psum_kernel(const int* __restrict__ counts,
                                                   int* __restrict__ psums) {
    int idx = blockIdx.x * 256 + threadIdx.x;
    int x = (idx < NN) ? counts[idx] : 0;
    int lane = threadIdx.x & 63, wv = threadIdx.x >> 6;
    #pragma unroll
    for (int d = 1; d < 64; d <<= 1) x += __shfl_xor(x, d, 64);
    __shared__ int ws[4];
    if (lane == 0) ws[wv] = x;
    __syncthreads();
    if (threadIdx.x == 0) psums[blockIdx.x] = ws[0] + ws[1] + ws[2] + ws[3];
}

__global__ __launch_bounds__(256) void pscan_kernel(const int* __restrict__ psums,
                                                    int* __restrict__ offs,
                                                    int* __restrict__ row_ptr) {
    int t = threadIdx.x;
    int x = (t < NB) ? psums[t] : 0;
    int lane = t & 63, wv = t >> 6;
    int incl = x;
    #pragma unroll
    for (int d = 1; d < 64; d <<= 1) {
        int y = __shfl_up(incl, d, 64);
        if (lane >= d) incl += y;
    }
    __shared__ int ws[4];
    if (lane == 63) ws[wv] = incl;
    __syncthreads();
    int off = 0;
    for (int k = 0; k < wv; ++k) off += ws[k];
    if (t < NB) offs[t] = incl + off - x;   // exclusive
    if (t == 0) row_ptr[0] = 0;
}

__global__ __launch_bounds__(256) void pfin_kernel(const int* __restrict__ counts,
                                                   const int* __restrict__ offs,
                                                   int* __restrict__ row_ptr,
                                                   int* __restrict__ cursor) {
    int idx = blockIdx.x * 256 + threadIdx.x;
    int x = (idx < NN) ? counts[idx] : 0;
    int lane = threadIdx.x & 63, wv = threadIdx.x >> 6;
    int incl = x;
    #pragma unroll
    for (int d = 1; d < 64; d <<= 1) {
        int y = __shfl_up(incl, d, 64);
        if (lane >= d) incl += y;
    }
    __shared__ int ws[4];
    if (lane == 63) ws[wv] = incl;
    __syncthreads();
    int off = offs[blockIdx.x];
    for (int k = 0; k < wv; ++k) off += ws[k];
    if (idx < NN) {
        int v = off + incl;
        row_ptr[idx + 1] = v;
        cursor[idx] = v - x;
    }
}

// scatter + pkq build (layer-invariant): pkq[p] = {src<<10, rel<<10} byte offsets, CSR order
__global__ void scatter_pk_kernel(const int* __restrict__ ei, const int* __restrict__ etype,
                                  int* __restrict__ cursor, uint2* __restrict__ pkq) {
    int e = blockIdx.x * 256 + threadIdx.x;
    if (e < EE) {
        int d = ei[EE + e];
        int p = atomicAdd(&cursor[d], 1);
        uint2 v;
        v.x = (unsigned)ei[e] << 10;
        v.y = (unsigned)etype[e] << 10;
        pkq[p] = v;
    }
}

// ---------------- fused prep: hb, wconv, xe(bf16), counts=0, be ----------------
__global__ __launch_bounds__(256) void prep_misc_kernel(
    const float* __restrict__ x_flat,
    const float* __restrict__ Wl, const float* __restrict__ Wr,
    const float* __restrict__ rel_emb, const float* __restrict__ We,
    const float* __restrict__ att,
    unsigned short* __restrict__ hb, unsigned short* __restrict__ Wt,
    unsigned short* __restrict__ xeb, float* __restrict__ be,
    int* __restrict__ counts) {
    int b = blockIdx.x, t = threadIdx.x;
    if (b < PM_HB) {
        int idx = b * 256 + t;                      // < NN*DM/4
        float4 v = ((const float4*)x_flat)[idx];
        ushort4 o;
        o.x = f2b(v.x); o.y = f2b(v.y); o.z = f2b(v.z); o.w = f2b(v.w);
        ((ushort4*)hb)[idx] = o;
        return;
    }
    b -= PM_HB;
    if (b < PM_WC) {
        int idx = b * 256 + t;                      // < 4*DM*HDIM
        int m = idx >> 16;
        int r = idx & 65535;
        int c = r >> 7, k = r & 127;
        int l = m >> 1;
        const float* W = (m & 1) ? Wr : Wl;
        Wt[idx] = f2b(W[(size_t)l * DM * HDIM + k * HDIM + c]);
        return;
    }
    b -= PM_WC;
    if (b < PM_XE) {
        int idx = b * 256 + t;                      // < LAYERS*NRELS*HDIM
        int l  = idx / (NRELS * HDIM);
        int r  = (idx / HDIM) & (NRELS - 1);
        int hc = idx & (HDIM - 1);
        const float* Wel = We + (size_t)l * RDIM * HDIM;
        float s = 0.f;
        #pragma unroll 8
        for (int d = 0; d < RDIM; ++d) s += rel_emb[r * RDIM + d] * Wel[d * HDIM + hc];
        xeb[idx] = f2b(s);
        return;
    }
    b -= PM_XE;
    if (b < PM_CZ) {
        int idx = b * 256 + t;
        if (idx < NN) counts[idx] = 0;
        return;
    }
    // be block
    __shared__ float aw_s[LAYERS * NH * RDIM];      // 512
    #pragma unroll
    for (int k = 0; k < 2; ++k) {
        int idx = t * 2 + k;                        // < 512
        int l = idx >> 8, h = (idx >> 6) & 3, d = idx & 63;
        const float* ap = att + (size_t)l * HDIM + h * DM;
        const float* wp = We + (size_t)l * RDIM * HDIM + (size_t)d * HDIM + h * DM;
        float s = 0.f;
        #pragma unroll 8
        for (int c = 0; c < DM; ++c) s += ap[c] * wp[c];
        aw_s[idx] = s;
    }
    __syncthreads();
    #pragma unroll
    for (int k = 0; k < 2; ++k) {
        int idx = t * 2 + k;                        // < 512 = L*NRELS*NH
        int l = idx >> 8, r = (idx >> 2) & 63, h = idx & 3;
        const float* rp = rel_emb + r * RDIM;
        const float* ap = aw_s + l * 256 + h * 64;
        float s = 0.f;
        #pragma unroll 8
        for (int d = 0; d < RDIM; ++d) s += rp[d] * ap[d];
        be[idx] = 0.6f * s;
    }
}

// ---------------- GEMM (M=32 tile, R8 known-good) + fused ab ----------------
__global__ __launch_bounds__(256) void gemm_xlxr_ab_kernel(
    const unsigned short* __restrict__ hb,        // [NN,128] bf16
    const unsigned short* __restrict__ WtL,       // [512][128] bf16 (transposed)
    const unsigned short* __restrict__ WtR,
    const float* __restrict__ bl, const float* __restrict__ br,
    const float* __restrict__ att_l,              // [512]
    unsigned short* __restrict__ xl, unsigned short* __restrict__ xr,
    float* __restrict__ ab) {
    int w = threadIdx.x >> 6, lane = threadIdx.x & 63;   // wave w owns head w
    int m0 = blockIdx.x * 32;
    int colL = lane & 15, kg = lane >> 4;

    frag8 a[2][4];
    #pragma unroll
    for (int mt = 0; mt < 2; ++mt) {
        int row = m0 + mt * 16 + colL;
        if (row >= NN) row = NN - 1;
        const unsigned short* arow = hb + (size_t)row * DM;
        #pragma unroll
        for (int kc = 0; kc < 4; ++kc) {
            uint4 raw = *(const uint4*)(arow + kc * 32 + kg * 8);
            a[mt][kc] = __builtin_bit_cast(frag8, raw);
        }
    }

    float prow[2][2][4];   // [mt][mat][r]
    #pragma unroll
    for (int mt = 0; mt < 2; ++mt)
        #pragma unroll
        for (int mat = 0; mat < 2; ++mat)
            #pragma unroll
            for (int r = 0; r < 4; ++r) prow[mt][mat][r] = 0.f;

    #pragma unroll
    for (int mat = 0; mat < 2; ++mat) {
        const unsigned short* Wt = mat ? WtR : WtL;
        const float* bias = mat ? br : bl;
        unsigned short* out = mat ? xr : xl;
        #pragma unroll
        for (int nt = 0; nt < 8; ++nt) {
            int col = w * 128 + nt * 16 + colL;
            f32x4 acc0 = {0.f, 0.f, 0.f, 0.f};
            f32x4 acc1 = {0.f, 0.f, 0.f, 0.f};
            #pragma unroll
            for (int kc = 0; kc < 4; ++kc) {
                uint4 raw = *(const uint4*)(Wt + (size_t)col * DM + kc * 32 + kg * 8);
                frag8 b = __builtin_bit_cast(frag8, raw);
                acc0 = __builtin_amdgcn_mfma_f32_16x16x32_bf16(a[0][kc], b, acc0, 0, 0, 0);
                acc1 = __builtin_amdgcn_mfma_f32_16x16x32_bf16(a[1][kc], b, acc1, 0, 0, 0);
            }
            float bb = bias[col];
            float ac = att_l[col];
            #pragma unroll
            for (int r = 0; r < 4; ++r) {
                float v0 = acc0[r] + bb;
                float v1 = acc1[r] + bb;
                int row0 = m0 + kg * 4 + r;
                int row1 = row0 + 16;
                if (row0 < NN) out[(size_t)row0 * HDIM + col] = f2b(v0);
                if (row1 < NN) out[(size_t)row1 * HDIM + col] = f2b(v1);
                prow[0][mat][r] = fmaf(ac, v0, prow[0][mat][r]);
                prow[1][mat][r] = fmaf(ac, v1, prow[1][mat][r]);
            }
        }
    }
    #pragma unroll
    for (int d = 1; d < 16; d <<= 1) {
        #pragma unroll
        for (int mt = 0; mt < 2; ++mt)
            #pragma unroll
            for (int mat = 0; mat < 2; ++mat)
                #pragma unroll
                for (int r = 0; r < 4; ++r)
                    prow[mt][mat][r] += __shfl_xor(prow[mt][mat][r], d, 64);
    }
    if (colL == 0) {
        #pragma unroll
        for (int mt = 0; mt < 2; ++mt) {
            int row = m0 + mt * 16 + kg * 4;
            #pragma unroll
            for (int mat = 0; mat < 2; ++mat)
                #pragma unroll
                for (int r = 0; r < 4; ++r)
                    if (row + r < NN)
                        ab[(size_t)(row + r) * 8 + mat * 4 + w] = 0.6f * prow[mt][mat][r];
        }
    }
}

// ------- fused per-node: per-WAVE strided node loop (no atomics, no block coupling) -------
__global__ __launch_bounds__(256) void node_fused_kernel(
    const int* __restrict__ row_ptr,
    const uint2* __restrict__ pkq,           // [EE] {src<<10, rel<<10}, CSR order
    const unsigned short* __restrict__ xl,   // [NN][512] bf16
    const unsigned short* __restrict__ xr,   // [NN][512] bf16
    const unsigned short* __restrict__ xeb_l,// [64][512] bf16 (this layer)
    const float* __restrict__ ab,            // [NN][8] f32 (dst part at +4)
    const float* __restrict__ be_l,          // [64][4] f32 (this layer)
    const float* __restrict__ att_l,         // [512] (this layer)
    const float* __restrict__ h_in,          // [NN][128]
    const float* __restrict__ b_out, const float* __restrict__ ln_g,
    const float* __restrict__ ln_b,
    float* __restrict__ h_out,
    unsigned short* __restrict__ hb_out) {
    int w = threadIdx.x >> 6, l = threadIdx.x & 63;
    int gw = blockIdx.x * 4 + w;            // global wave id, 0..NWAVES-1
    int hh = l >> 4;
    __shared__ float cl[4][64][4];
    __shared__ uint2 pk_s[4][64];

    int c0 = (l & 15) * 8;

    // node-invariant loads (hoisted)
    float4 at0 = ((const float4*)(att_l + l * 8))[0];
    float4 at1 = ((const float4*)(att_l + l * 8))[1];
    float atv[8] = {at0.x * 0.4f, at0.y * 0.4f, at0.z * 0.4f, at0.w * 0.4f,
                    at1.x * 0.4f, at1.y * 0.4f, at1.z * 0.4f, at1.w * 0.4f};
    float4 bo0 = *(const float4*)(b_out + c0);
    float4 bo1 = *(const float4*)(b_out + c0 + 4);
    float bov[8] = {bo0.x, bo0.y, bo0.z, bo0.w, bo1.x, bo1.y, bo1.z, bo1.w};
    float4 g0 = *(const float4*)(ln_g + c0);
    float4 g1 = *(const float4*)(ln_g + c0 + 4);
    float4 q0 = *(const float4*)(ln_b + c0);
    float4 q1 = *(const float4*)(ln_b + c0 + 4);

    const char* xl_b = (const char*)xl;
    const char* xe_b = (const char*)xeb_l;
    uint l16 = (uint)l << 4;

    for (int i = gw; i < NN; i += NWAVES) {
        int beg = row_ptr[i], end = row_ptr[i + 1];

        uint4 xrv = *(const uint4*)(xr + (size_t)i * HDIM + l * 8);
        f32x2 xrp0 = f32x2{b2f_lo(xrv.x), b2f_hi(xrv.x)};
        f32x2 xrp1 = f32x2{b2f_lo(xrv.y), b2f_hi(xrv.y)};
        f32x2 xrp2 = f32x2{b2f_lo(xrv.z), b2f_hi(xrv.z)};
        f32x2 xrp3 = f32x2{b2f_lo(xrv.w), b2f_hi(xrv.w)};
        float4 bxv = ((const float4*)ab)[2 * i + 1];   // 0.6 att.xr_i per head
        float4 hv0 = *(const float4*)(h_in + (size_t)i * DM + c0);
        float4 hv1 = *(const float4*)(h_in + (size_t)i * DM + c0 + 4);

        float ss = 0.f;
        f32x2 acc0 = f32x2{0.f, 0.f}, acc1 = f32x2{0.f, 0.f};
        f32x2 acc2 = f32x2{0.f, 0.f}, acc3 = f32x2{0.f, 0.f};

        for (int cb = beg; cb < end; cb += 64) {
            int mc = min(64, end - cb);
            if (l < mc) {
                uint2 pk = pkq[cb + l];
                pk_s[w][l] = pk;
                int s = pk.x >> 10, r = pk.y >> 10;
                float4 a4 = ((const float4*)ab)[2 * s];
                float4 b4 = ((const float4*)be_l)[r];
                cl[w][l][0] = a4.x + b4.x + bxv.x;
                cl[w][l][1] = a4.y + b4.y + bxv.y;
                cl[w][l][2] = a4.z + b4.z + bxv.z;
                cl[w][l][3] = a4.w + b4.w + bxv.w;
            }
            // 2-deep pipeline over edges (wave-synchronous, no barrier)
            uint2 pk0 = pk_s[w][0];
            uint4 vvP = *(const uint4*)(xl_b + pk0.x + l16);
            uint4 eeP = *(const uint4*)(xe_b + pk0.y + l16);
            float cjP = cl[w][0][hh];
            for (int j = 1; j <= mc; ++j) {
                uint4 vv = vvP; uint4 ee = eeP; float cj = cjP;
                if (j < mc) {
                    uint2 pkj = pk_s[w][j];
                    vvP = *(const uint4*)(xl_b + pkj.x + l16);
                    eeP = *(const uint4*)(xe_b + pkj.y + l16);
                    cjP = cl[w][j][hh];
                }
                f32x2 xp0 = f32x2{b2f_lo(vv.x), b2f_hi_raw(vv.x)};
                f32x2 xp1 = f32x2{b2f_lo(vv.y), b2f_hi_raw(vv.y)};
                f32x2 xp2 = f32x2{b2f_lo(vv.z), b2f_hi_raw(vv.z)};
                f32x2 xp3 = f32x2{b2f_lo(vv.w), b2f_hi_raw(vv.w)};
                f32x2 z0 = (xp0 + xrp0) + f32x2{b2f_lo(ee.x), b2f_hi_raw(ee.x)};
                f32x2 z1 = (xp1 + xrp1) + f32x2{b2f_lo(ee.y), b2f_hi_raw(ee.y)};
                f32x2 z2 = (xp2 + xrp2) + f32x2{b2f_lo(ee.z), b2f_hi_raw(ee.z)};
                f32x2 z3 = (xp3 + xrp3) + f32x2{b2f_lo(ee.w), b2f_hi_raw(ee.w)};
                float partial = fmaf(atv[0], fabsf(z0[0]),
                                fmaf(atv[1], fabsf(z0[1]),
                                fmaf(atv[2], fabsf(z1[0]),
                                fmaf(atv[3], fabsf(z1[1]),
                                fmaf(atv[4], fabsf(z2[0]),
                                fmaf(atv[5], fabsf(z2[1]),
                                fmaf(atv[6], fabsf(z3[0]), atv[7] * fabsf(z3[1]))))))));
                partial = dpp_add<0xB1>(partial);
                partial = dpp_add<0x4E>(partial);
                partial = dpp_add<0x124>(partial);
                partial = dpp_add<0x128>(partial);
                float we = __expf(partial + cj);
                ss += we;
                f32x2 wv = f32x2{we, we};
                acc0 += wv * xp0;
                acc1 += wv * xp1;
                acc2 += wv * xp2;
                acc3 += wv * xp3;
            }
        }

        // normalize per head, then sum across the 4 head groups (lanes ^16, ^32)
        float invs = (ss > 0.f) ? 1.f / ss : 0.f;
        float sv[8] = {acc0[0] * invs, acc0[1] * invs, acc1[0] * invs, acc1[1] * invs,
                       acc2[0] * invs, acc2[1] * invs, acc3[0] * invs, acc3[1] * invs};
        #pragma unroll
        for (int d = 16; d < 64; d <<= 1)
            #pragma unroll
            for (int k = 0; k < 8; ++k) sv[k] += __shfl_xor(sv[k], d, 64);

        float hvv[8] = {hv0.x, hv0.y, hv0.z, hv0.w, hv1.x, hv1.y, hv1.z, hv1.w};
        float yv[8];
        float la = 0.f, lb = 0.f;
        #pragma unroll
        for (int k = 0; k < 8; ++k) {
            float o = sv[k] * 0.25f + bov[k];
            float ge = 0.5f * o * (1.f + erff(o * 0.70710678118654752f));
            float y = hvv[k] + ge;
            yv[k] = y; la += y; lb += y * y;
        }
        la = dpp_add<0xB1>(la); la = dpp_add<0x4E>(la);
        la = dpp_add<0x124>(la); la = dpp_add<0x128>(la);
        lb = dpp_add<0xB1>(lb); lb = dpp_add<0x4E>(lb);
        lb = dpp_add<0x124>(lb); lb = dpp_add<0x128>(lb);
        float mean = la * (1.f / 128.f);
        float var = lb * (1.f / 128.f) - mean * mean;
        float rs = rsqrtf(var + 1e-5f);

        if (l < 16) {
            float gv[8] = {g0.x, g0.y, g0.z, g0.w, g1.x, g1.y, g1.z, g1.w};
            float qv[8] = {q0.x, q0.y, q0.z, q0.w, q1.x, q1.y, q1.z, q1.w};
            float ov[8];
            #pragma unroll
            for (int k = 0; k < 8; ++k)
                ov[k] = (yv[k] - mean) * rs * gv[k] + qv[k];
            float* hop = h_out + (size_t)i * DM + c0;
            *(float4*)hop = make_float4(ov[0], ov[1], ov[2], ov[3]);
            *(float4*)(hop + 4) = make_float4(ov[4], ov[5], ov[6], ov[7]);
            uint4 ob;
            ob.x = (unsigned)f2b(ov[0]) | ((unsigned)f2b(ov[1]) << 16);
            ob.y = (unsigned)f2b(ov[2]) | ((unsigned)f2b(ov[3]) << 16);
            ob.z = (unsigned)f2b(ov[4]) | ((unsigned)f2b(ov[5]) << 16);
            ob.w = (unsigned)f2b(ov[6]) | ((unsigned)f2b(ov[7]) << 16);
            *(uint4*)(hb_out + (size_t)i * DM + c0) = ob;
        }
    }
}

// ---------------- launch ----------------
extern "C" void kernel_launch(void* const* d_in, const int* in_sizes, int n_in,
                              void* d_out, int out_size, void* d_ws, size_t ws_size,
                              hipStream_t stream) {
    const float* x_flat   = (const float*)d_in[0];
    const int*   edge_idx = (const int*)d_in[1];
    const int*   edge_ty  = (const int*)d_in[2];
    const float* rel_emb  = (const float*)d_in[3];
    const float* Wl       = (const float*)d_in[4];
    const float* bl       = (const float*)d_in[5];
    const float* Wr       = (const float*)d_in[6];
    const float* br       = (const float*)d_in[7];
    const float* We       = (const float*)d_in[8];
    const float* att      = (const float*)d_in[9];
    const float* b_out    = (const float*)d_in[10];
    const float* ln_g     = (const float*)d_in[11];
    const float* ln_b     = (const float*)d_in[12];

    char* p = (char*)d_ws;
    auto carve = [&](size_t bytes) {
        void* r = (void*)p;
        p += (bytes + 255) & ~(size_t)255;
        return r;
    };
    unsigned short* xl     = (unsigned short*)carve((size_t)NN * HDIM * 2);
    unsigned short* xr     = (unsigned short*)carve((size_t)NN * HDIM * 2);
    float*          h1     = (float*)carve((size_t)NN * DM * 4);
    unsigned short* hb     = (unsigned short*)carve((size_t)NN * DM * 2);
    unsigned short* Wt     = (unsigned short*)carve((size_t)4 * DM * HDIM * 2);
    unsigned short* xeb    = (unsigned short*)carve((size_t)LAYERS * NRELS * HDIM * 2);
    float*          ab     = (float*)carve((size_t)NN * 8 * 4);
    float*          be     = (float*)carve((size_t)LAYERS * NRELS * NH * 4);
    int*            row_ptr= (int*)carve((size_t)(NN + 1) * 4);
    int*            counts = (int*)carve((size_t)NN * 4);
    int*            cursor = (int*)carve((size_t)NN * 4);
    int*            psums  = (int*)carve((size_t)NB * 4);
    int*            offs   = (int*)carve((size_t)NB * 4);
    uint2*          pkq    = (uint2*)carve((size_t)EE * 8);

    const int* dst = edge_idx + EE;

    // fused prep (hb, Wt, xeb, be, counts=0)
    prep_misc_kernel<<<PM_TOT, 256, 0, stream>>>(
        x_flat, Wl, Wr, rel_emb, We, att, hb, Wt, xeb, be, counts);

    // CSR build (parallel scan) + pkq
    count_kernel<<<(EE + 255) / 256, 256, 0, stream>>>(dst, counts);
    psum_kernel<<<NB, 256, 0, stream>>>(counts, psums);
    pscan_kernel<<<1, 256, 0, stream>>>(psums, offs, row_ptr);
    pfin_kernel<<<NB, 256, 0, stream>>>(counts, offs, row_ptr, cursor);
    scatter_pk_kernel<<<(EE + 255) / 256, 256, 0, stream>>>(edge_idx, edge_ty, cursor, pkq);

    const float* h_cur = x_flat;
    for (int l = 0; l < LAYERS; ++l) {
        float* h_next = (l == LAYERS - 1) ? (float*)d_out : h1;
        gemm_xlxr_ab_kernel<<<(NN + 31) / 32, 256, 0, stream>>>(
            hb,
            Wt + (size_t)(l * 2 + 0) * DM * HDIM,
            Wt + (size_t)(l * 2 + 1) * DM * HDIM,
            bl + (size_t)l * HDIM, br + (size_t)l * HDIM,
            att + (size_t)l * HDIM,
            xl, xr, ab);
        node_fused_kernel<<<2048, 256, 0, stream>>>(
            row_ptr, pkq, xl, xr,
            xeb + (size_t)l * NRELS * HDIM,
            ab, be + (size_t)l * NRELS * NH,
            att + (size_t)l * HDIM,
            h_cur,
            b_out + (size_t)l * DM, ln_g + (size_t)l * DM, ln_b + (size_t)l * DM,
            h_next, hb);
        h_cur = h_next;
    }
}

// Round 13
// 561.214 us; speedup vs baseline: 2.9428x; 1.0566x over previous
//
#include <hip/hip_runtime.h>
#include <hip/hip_bf16.h>

#define NN 50000
#define DM 128
#define EE 800000
#define NH 4
#define HDIM 512      // NH * DM
#define NRELS 64
#define RDIM 64
#define LAYERS 2
#define NB 196        // ceil(NN/256)

// prep_misc block ranges
#define PM_HB 6250    // NN*DM/4/256
#define PM_WC 1024    // 4*DM*HDIM/256
#define PM_XE 256     // LAYERS*NRELS*HDIM/256
#define PM_CZ 196     // NB
#define PM_TOT (PM_HB + PM_WC + PM_XE + PM_CZ + 1)

typedef short frag8 __attribute__((ext_vector_type(8)));   // 8 bf16 (bits)
typedef float f32x4 __attribute__((ext_vector_type(4)));
typedef float f32x2 __attribute__((ext_vector_type(2)));

__device__ __forceinline__ float b2f(unsigned short u) {
    unsigned v = ((unsigned)u) << 16;
    union { unsigned u; float f; } c; c.u = v; return c.f;
}
__device__ __forceinline__ float b2f_lo(unsigned u) {
    union { unsigned u; float f; } c; c.u = u << 16; return c.f;
}
__device__ __forceinline__ float b2f_hi(unsigned u) {
    union { unsigned u; float f; } c; c.u = u & 0xFFFF0000u; return c.f;
}
__device__ __forceinline__ unsigned short f2b(float f) {
    union { float f; unsigned u; } c; c.f = f;
    unsigned u = c.u;
    u += 0x7FFFu + ((u >> 16) & 1u);   // round-to-nearest-even
    return (unsigned short)(u >> 16);
}

// DPP 16-lane row sum-reduce step (pure VALU, no DS)
template<int CTRL>
__device__ __forceinline__ float dpp_add(float x) {
    int yi = __builtin_amdgcn_update_dpp(0, __builtin_bit_cast(int, x),
                                         CTRL, 0xF, 0xF, true);
    return x + __builtin_bit_cast(float, yi);
}

// ---------------- CSR build ----------------
__global__ void count_kernel(const int* __restrict__ dst, int* __restrict__ counts) {
    int e = blockIdx.x * 256 + threadIdx.x;
    if (e < EE) atomicAdd(&counts[dst[e]], 1);
}

__global__ __launch_bounds__(256) void psum_kernel(const int* __restrict__ counts,
                                                   int* __restrict__ psums) {
    int idx = blockIdx.x * 256 + threadIdx.x;
    int x = (idx < NN) ? counts[idx] : 0;
    int lane = threadIdx.x & 63, wv = threadIdx.x >> 6;
    #pragma unroll
    for (int d = 1; d < 64; d <<= 1) x += __shfl_xor(x, d, 64);
    __shared__ int ws[4];
    if (lane == 0) ws[wv] = x;
    __syncthreads();
    if (threadIdx.x == 0) psums[blockIdx.x] = ws[0] + ws[1] + ws[2] + ws[3];
}

__global__ __launch_bounds__(256) void pscan_kernel(const int* __restrict__ psums,
                                                    int* __restrict__ offs,
                                                    int* __restrict__ row_ptr) {
    int t = threadIdx.x;
    int x = (t < NB) ? psums[t] : 0;
    int lane = t & 63, wv = t >> 6;
    int incl = x;
    #pragma unroll
    for (int d = 1; d < 64; d <<= 1) {
        int y = __shfl_up(incl, d, 64);
        if (lane >= d) incl += y;
    }
    __shared__ int ws[4];
    if (lane == 63) ws[wv] = incl;
    __syncthreads();
    int off = 0;
    for (int k = 0; k < wv; ++k) off += ws[k];
    if (t < NB) offs[t] = incl + off - x;   // exclusive
    if (t == 0) row_ptr[0] = 0;
}

__global__ __launch_bounds__(256) void pfin_kernel(const int* __restrict__ counts,
                                                   const int* __restrict__ offs,
                                                   int* __restrict__ row_ptr,
                                                   int* __restrict__ cursor) {
    int idx = blockIdx.x * 256 + threadIdx.x;
    int x = (idx < NN) ? counts[idx] : 0;
    int lane = threadIdx.x & 63, wv = threadIdx.x >> 6;
    int incl = x;
    #pragma unroll
    for (int d = 1; d < 64; d <<= 1) {
        int y = __shfl_up(incl, d, 64);
        if (lane >= d) incl += y;
    }
    __shared__ int ws[4];
    if (lane == 63) ws[wv] = incl;
    __syncthreads();
    int off = offs[blockIdx.x];
    for (int k = 0; k < wv; ++k) off += ws[k];
    if (idx < NN) {
        int v = off + incl;
        row_ptr[idx + 1] = v;
        cursor[idx] = v - x;
    }
}

// scatter + pkq build (layer-invariant): pkq[p] = (src<<6)|rel in CSR order
__global__ void scatter_pk_kernel(const int* __restrict__ ei, const int* __restrict__ etype,
                                  int* __restrict__ cursor, unsigned* __restrict__ pkq) {
    int e = blockIdx.x * 256 + threadIdx.x;
    if (e < EE) {
        int d = ei[EE + e];
        int p = atomicAdd(&cursor[d], 1);
        pkq[p] = ((unsigned)ei[e] << 6) | (unsigned)etype[e];
    }
}

// ---------------- fused prep: hb, wconv, xe(bf16), counts=0, be ----------------
__global__ __launch_bounds__(256) void prep_misc_kernel(
    const float* __restrict__ x_flat,
    const float* __restrict__ Wl, const float* __restrict__ Wr,
    const float* __restrict__ rel_emb, const float* __restrict__ We,
    const float* __restrict__ att,
    unsigned short* __restrict__ hb, unsigned short* __restrict__ Wt,
    unsigned short* __restrict__ xeb, float* __restrict__ be,
    int* __restrict__ counts) {
    int b = blockIdx.x, t = threadIdx.x;
    if (b < PM_HB) {
        int idx = b * 256 + t;                      // < NN*DM/4
        float4 v = ((const float4*)x_flat)[idx];
        ushort4 o;
        o.x = f2b(v.x); o.y = f2b(v.y); o.z = f2b(v.z); o.w = f2b(v.w);
        ((ushort4*)hb)[idx] = o;
        return;
    }
    b -= PM_HB;
    if (b < PM_WC) {
        int idx = b * 256 + t;                      // < 4*DM*HDIM
        int m = idx >> 16;
        int r = idx & 65535;
        int c = r >> 7, k = r & 127;
        int l = m >> 1;
        const float* W = (m & 1) ? Wr : Wl;
        Wt[idx] = f2b(W[(size_t)l * DM * HDIM + k * HDIM + c]);
        return;
    }
    b -= PM_WC;
    if (b < PM_XE) {
        int idx = b * 256 + t;                      // < LAYERS*NRELS*HDIM
        int l  = idx / (NRELS * HDIM);
        int r  = (idx / HDIM) & (NRELS - 1);
        int hc = idx & (HDIM - 1);
        const float* Wel = We + (size_t)l * RDIM * HDIM;
        float s = 0.f;
        #pragma unroll 8
        for (int d = 0; d < RDIM; ++d) s += rel_emb[r * RDIM + d] * Wel[d * HDIM + hc];
        xeb[idx] = f2b(s);
        return;
    }
    b -= PM_XE;
    if (b < PM_CZ) {
        int idx = b * 256 + t;
        if (idx < NN) counts[idx] = 0;
        return;
    }
    // be block: aw[l][h][d] = sum_c att[l][h][c]*We[l][d][h*128+c];
    // be[l][r][h] = 0.6 * sum_d rel_emb[r][d]*aw[l][h][d]
    __shared__ float aw_s[LAYERS * NH * RDIM];      // 512
    #pragma unroll
    for (int k = 0; k < 2; ++k) {
        int idx = t * 2 + k;                        // < 512
        int l = idx >> 8, h = (idx >> 6) & 3, d = idx & 63;
        const float* ap = att + (size_t)l * HDIM + h * DM;
        const float* wp = We + (size_t)l * RDIM * HDIM + (size_t)d * HDIM + h * DM;
        float s = 0.f;
        #pragma unroll 8
        for (int c = 0; c < DM; ++c) s += ap[c] * wp[c];
        aw_s[idx] = s;
    }
    __syncthreads();
    #pragma unroll
    for (int k = 0; k < 2; ++k) {
        int idx = t * 2 + k;                        // < 512 = L*NRELS*NH
        int l = idx >> 8, r = (idx >> 2) & 63, h = idx & 3;
        const float* rp = rel_emb + r * RDIM;
        const float* ap = aw_s + l * 256 + h * 64;
        float s = 0.f;
        #pragma unroll 8
        for (int d = 0; d < RDIM; ++d) s += rp[d] * ap[d];
        be[idx] = 0.6f * s;
    }
}

// ---------------- GEMM (M=32 tile) + fused ab ----------------
__global__ __launch_bounds__(256) void gemm_xlxr_ab_kernel(
    const unsigned short* __restrict__ hb,        // [NN,128] bf16
    const unsigned short* __restrict__ WtL,       // [512][128] bf16 (transposed)
    const unsigned short* __restrict__ WtR,
    const float* __restrict__ bl, const float* __restrict__ br,
    const float* __restrict__ att_l,              // [512]
    unsigned short* __restrict__ xl, unsigned short* __restrict__ xr,
    float* __restrict__ ab) {
    int w = threadIdx.x >> 6, lane = threadIdx.x & 63;   // wave w owns head w
    int m0 = blockIdx.x * 32;
    int colL = lane & 15, kg = lane >> 4;

    frag8 a[2][4];
    #pragma unroll
    for (int mt = 0; mt < 2; ++mt) {
        int row = m0 + mt * 16 + colL;
        if (row >= NN) row = NN - 1;
        const unsigned short* arow = hb + (size_t)row * DM;
        #pragma unroll
        for (int kc = 0; kc < 4; ++kc) {
            uint4 raw = *(const uint4*)(arow + kc * 32 + kg * 8);
            a[mt][kc] = __builtin_bit_cast(frag8, raw);
        }
    }

    float prow[2][2][4];   // [mt][mat][r]
    #pragma unroll
    for (int mt = 0; mt < 2; ++mt)
        #pragma unroll
        for (int mat = 0; mat < 2; ++mat)
            #pragma unroll
            for (int r = 0; r < 4; ++r) prow[mt][mat][r] = 0.f;

    #pragma unroll
    for (int mat = 0; mat < 2; ++mat) {
        const unsigned short* Wt = mat ? WtR : WtL;
        const float* bias = mat ? br : bl;
        unsigned short* out = mat ? xr : xl;
        #pragma unroll
        for (int nt = 0; nt < 8; ++nt) {
            int col = w * 128 + nt * 16 + colL;
            f32x4 acc0 = {0.f, 0.f, 0.f, 0.f};
            f32x4 acc1 = {0.f, 0.f, 0.f, 0.f};
            #pragma unroll
            for (int kc = 0; kc < 4; ++kc) {
                uint4 raw = *(const uint4*)(Wt + (size_t)col * DM + kc * 32 + kg * 8);
                frag8 b = __builtin_bit_cast(frag8, raw);
                acc0 = __builtin_amdgcn_mfma_f32_16x16x32_bf16(a[0][kc], b, acc0, 0, 0, 0);
                acc1 = __builtin_amdgcn_mfma_f32_16x16x32_bf16(a[1][kc], b, acc1, 0, 0, 0);
            }
            float bb = bias[col];
            float ac = att_l[col];
            #pragma unroll
            for (int r = 0; r < 4; ++r) {
                float v0 = acc0[r] + bb;
                float v1 = acc1[r] + bb;
                int row0 = m0 + kg * 4 + r;
                int row1 = row0 + 16;
                if (row0 < NN) out[(size_t)row0 * HDIM + col] = f2b(v0);
                if (row1 < NN) out[(size_t)row1 * HDIM + col] = f2b(v1);
                prow[0][mat][r] = fmaf(ac, v0, prow[0][mat][r]);
                prow[1][mat][r] = fmaf(ac, v1, prow[1][mat][r]);
            }
        }
    }
    #pragma unroll
    for (int d = 1; d < 16; d <<= 1) {
        #pragma unroll
        for (int mt = 0; mt < 2; ++mt)
            #pragma unroll
            for (int mat = 0; mat < 2; ++mat)
                #pragma unroll
                for (int r = 0; r < 4; ++r)
                    prow[mt][mat][r] += __shfl_xor(prow[mt][mat][r], d, 64);
    }
    if (colL == 0) {
        #pragma unroll
        for (int mt = 0; mt < 2; ++mt) {
            int row = m0 + mt * 16 + kg * 4;
            #pragma unroll
            for (int mat = 0; mat < 2; ++mat)
                #pragma unroll
                for (int r = 0; r < 4; ++r)
                    if (row + r < NN)
                        ab[(size_t)(row + r) * 8 + mat * 4 + w] = 0.6f * prow[mt][mat][r];
        }
    }
}

// ------- fused per-node: one WAVE per node, 4 nodes/block, no barriers, DPP reduce -------
__global__ __launch_bounds__(256) void node_fused_kernel(
    const int* __restrict__ row_ptr,
    const unsigned* __restrict__ pkq,        // [EE] packed (src<<6)|rel, CSR order
    const unsigned short* __restrict__ xl,   // [NN][512] bf16
    const unsigned short* __restrict__ xr,   // [NN][512] bf16
    const unsigned short* __restrict__ xeb_l,// [64][512] bf16 (this layer)
    const float* __restrict__ ab,            // [NN][8] f32 (dst part at +4)
    const float* __restrict__ be_l,          // [64][4] f32 (this layer)
    const float* __restrict__ att_l,         // [512] (this layer)
    const float* __restrict__ h_in,          // [NN][128]
    const float* __restrict__ b_out, const float* __restrict__ ln_g,
    const float* __restrict__ ln_b,
    float* __restrict__ h_out,
    unsigned short* __restrict__ hb_out) {
    int w = threadIdx.x >> 6, l = threadIdx.x & 63;
    int i = blockIdx.x * 4 + w;
    int hh = l >> 4;
    __shared__ float cl[4][64][4];
    __shared__ unsigned pk_s[4][64];

    int beg = row_ptr[i], end = row_ptr[i + 1];
    int c0 = (l & 15) * 8;

    uint4 xrv = *(const uint4*)(xr + (size_t)i * HDIM + l * 8);
    f32x2 xrp0 = f32x2{b2f_lo(xrv.x), b2f_hi(xrv.x)};
    f32x2 xrp1 = f32x2{b2f_lo(xrv.y), b2f_hi(xrv.y)};
    f32x2 xrp2 = f32x2{b2f_lo(xrv.z), b2f_hi(xrv.z)};
    f32x2 xrp3 = f32x2{b2f_lo(xrv.w), b2f_hi(xrv.w)};
    float4 at0 = ((const float4*)(att_l + l * 8))[0];
    float4 at1 = ((const float4*)(att_l + l * 8))[1];
    float atv[8] = {at0.x * 0.4f, at0.y * 0.4f, at0.z * 0.4f, at0.w * 0.4f,
                    at1.x * 0.4f, at1.y * 0.4f, at1.z * 0.4f, at1.w * 0.4f};
    float4 bxv = ((const float4*)ab)[2 * i + 1];   // 0.6 att.xr_i per head
    float4 hv0 = *(const float4*)(h_in + (size_t)i * DM + c0);      // early issue
    float4 hv1 = *(const float4*)(h_in + (size_t)i * DM + c0 + 4);

    const char* xl_b = (const char*)xl;
    const char* xe_b = (const char*)xeb_l;
    uint l16 = (uint)l << 4;

    float ss = 0.f;
    f32x2 acc0 = f32x2{0.f, 0.f}, acc1 = f32x2{0.f, 0.f};
    f32x2 acc2 = f32x2{0.f, 0.f}, acc3 = f32x2{0.f, 0.f};

    for (int cb = beg; cb < end; cb += 64) {
        int mc = min(64, end - cb);
        if (l < mc) {
            unsigned pk = pkq[cb + l];
            pk_s[w][l] = pk;
            int s = pk >> 6, r = pk & 63;
            float4 a4 = ((const float4*)ab)[2 * s];
            float4 b4 = ((const float4*)be_l)[r];
            cl[w][l][0] = a4.x + b4.x + bxv.x;
            cl[w][l][1] = a4.y + b4.y + bxv.y;
            cl[w][l][2] = a4.z + b4.z + bxv.z;
            cl[w][l][3] = a4.w + b4.w + bxv.w;
        }
        // 2-deep pipeline over edges (wave-synchronous, no barrier)
        unsigned pk0 = pk_s[w][0];
        uint4 vvP = *(const uint4*)(xl_b + ((pk0 >> 6) << 10) + l16);
        uint4 eeP = *(const uint4*)(xe_b + ((pk0 & 63u) << 10) + l16);
        float cjP = cl[w][0][hh];
        for (int j = 1; j <= mc; ++j) {
            uint4 vv = vvP; uint4 ee = eeP; float cj = cjP;
            if (j < mc) {
                unsigned pkj = pk_s[w][j];
                vvP = *(const uint4*)(xl_b + ((pkj >> 6) << 10) + l16);
                eeP = *(const uint4*)(xe_b + ((pkj & 63u) << 10) + l16);
                cjP = cl[w][j][hh];
            }
            f32x2 xp0 = f32x2{b2f_lo(vv.x), b2f_hi(vv.x)};
            f32x2 xp1 = f32x2{b2f_lo(vv.y), b2f_hi(vv.y)};
            f32x2 xp2 = f32x2{b2f_lo(vv.z), b2f_hi(vv.z)};
            f32x2 xp3 = f32x2{b2f_lo(vv.w), b2f_hi(vv.w)};
            f32x2 z0 = (xp0 + xrp0) + f32x2{b2f_lo(ee.x), b2f_hi(ee.x)};
            f32x2 z1 = (xp1 + xrp1) + f32x2{b2f_lo(ee.y), b2f_hi(ee.y)};
            f32x2 z2 = (xp2 + xrp2) + f32x2{b2f_lo(ee.z), b2f_hi(ee.z)};
            f32x2 z3 = (xp3 + xrp3) + f32x2{b2f_lo(ee.w), b2f_hi(ee.w)};
            float partial = fmaf(atv[0], fabsf(z0[0]),
                            fmaf(atv[1], fabsf(z0[1]),
                            fmaf(atv[2], fabsf(z1[0]),
                            fmaf(atv[3], fabsf(z1[1]),
                            fmaf(atv[4], fabsf(z2[0]),
                            fmaf(atv[5], fabsf(z2[1]),
                            fmaf(atv[6], fabsf(z3[0]), atv[7] * fabsf(z3[1]))))))));
            // 16-lane row reduce via DPP (xor1, xor2, ror4, ror8) — pure VALU
            partial = dpp_add<0xB1>(partial);
            partial = dpp_add<0x4E>(partial);
            partial = dpp_add<0x124>(partial);
            partial = dpp_add<0x128>(partial);
            float we = __expf(partial + cj);
            ss += we;
            f32x2 wv = f32x2{we, we};
            acc0 += wv * xp0;
            acc1 += wv * xp1;
            acc2 += wv * xp2;
            acc3 += wv * xp3;
        }
    }

    // normalize per head, then sum across the 4 head groups (lanes ^16, ^32)
    float invs = (ss > 0.f) ? 1.f / ss : 0.f;
    float sv[8] = {acc0[0] * invs, acc0[1] * invs, acc1[0] * invs, acc1[1] * invs,
                   acc2[0] * invs, acc2[1] * invs, acc3[0] * invs, acc3[1] * invs};
    #pragma unroll
    for (int d = 16; d < 64; d <<= 1)
        #pragma unroll
        for (int k = 0; k < 8; ++k) sv[k] += __shfl_xor(sv[k], d, 64);

    float4 bo0 = *(const float4*)(b_out + c0);
    float4 bo1 = *(const float4*)(b_out + c0 + 4);
    float bov[8] = {bo0.x, bo0.y, bo0.z, bo0.w, bo1.x, bo1.y, bo1.z, bo1.w};
    float hvv[8] = {hv0.x, hv0.y, hv0.z, hv0.w, hv1.x, hv1.y, hv1.z, hv1.w};
    float yv[8];
    float la = 0.f, lb = 0.f;
    #pragma unroll
    for (int k = 0; k < 8; ++k) {
        float o = sv[k] * 0.25f + bov[k];
        float ge = 0.5f * o * (1.f + erff(o * 0.70710678118654752f));
        float y = hvv[k] + ge;
        yv[k] = y; la += y; lb += y * y;
    }
    // sum within the 16-lane row (each row holds the full 128 channels)
    la = dpp_add<0xB1>(la); la = dpp_add<0x4E>(la);
    la = dpp_add<0x124>(la); la = dpp_add<0x128>(la);
    lb = dpp_add<0xB1>(lb); lb = dpp_add<0x4E>(lb);
    lb = dpp_add<0x124>(lb); lb = dpp_add<0x128>(lb);
    float mean = la * (1.f / 128.f);
    float var = lb * (1.f / 128.f) - mean * mean;
    float rs = rsqrtf(var + 1e-5f);

    if (l < 16) {
        float4 g0 = *(const float4*)(ln_g + c0);
        float4 g1 = *(const float4*)(ln_g + c0 + 4);
        float4 q0 = *(const float4*)(ln_b + c0);
        float4 q1 = *(const float4*)(ln_b + c0 + 4);
        float gv[8] = {g0.x, g0.y, g0.z, g0.w, g1.x, g1.y, g1.z, g1.w};
        float qv[8] = {q0.x, q0.y, q0.z, q0.w, q1.x, q1.y, q1.z, q1.w};
        float ov[8];
        #pragma unroll
        for (int k = 0; k < 8; ++k)
            ov[k] = (yv[k] - mean) * rs * gv[k] + qv[k];
        float* hop = h_out + (size_t)i * DM + c0;
        *(float4*)hop = make_float4(ov[0], ov[1], ov[2], ov[3]);
        *(float4*)(hop + 4) = make_float4(ov[4], ov[5], ov[6], ov[7]);
        uint4 ob;
        ob.x = (unsigned)f2b(ov[0]) | ((unsigned)f2b(ov[1]) << 16);
        ob.y = (unsigned)f2b(ov[2]) | ((unsigned)f2b(ov[3]) << 16);
        ob.z = (unsigned)f2b(ov[4]) | ((unsigned)f2b(ov[5]) << 16);
        ob.w = (unsigned)f2b(ov[6]) | ((unsigned)f2b(ov[7]) << 16);
        *(uint4*)(hb_out + (size_t)i * HDIM / 4 + c0) = ob;
    }
}

// ---------------- launch ----------------
extern "C" void kernel_launch(void* const* d_in, const int* in_sizes, int n_in,
                              void* d_out, int out_size, void* d_ws, size_t ws_size,
                              hipStream_t stream) {
    const float* x_flat   = (const float*)d_in[0];
    const int*   edge_idx = (const int*)d_in[1];
    const int*   edge_ty  = (const int*)d_in[2];
    const float* rel_emb  = (const float*)d_in[3];
    const float* Wl       = (const float*)d_in[4];
    const float* bl       = (const float*)d_in[5];
    const float* Wr       = (const float*)d_in[6];
    const float* br       = (const float*)d_in[7];
    const float* We       = (const float*)d_in[8];
    const float* att      = (const float*)d_in[9];
    const float* b_out    = (const float*)d_in[10];
    const float* ln_g     = (const float*)d_in[11];
    const float* ln_b     = (const float*)d_in[12];

    char* p = (char*)d_ws;
    auto carve = [&](size_t bytes) {
        void* r = (void*)p;
        p += (bytes + 255) & ~(size_t)255;
        return r;
    };
    unsigned short* xl     = (unsigned short*)carve((size_t)NN * HDIM * 2);
    unsigned short* xr     = (unsigned short*)carve((size_t)NN * HDIM * 2);
    float*          h1     = (float*)carve((size_t)NN * DM * 4);
    unsigned short* hb     = (unsigned short*)carve((size_t)NN * DM * 2);
    unsigned short* Wt     = (unsigned short*)carve((size_t)4 * DM * HDIM * 2);
    unsigned short* xeb    = (unsigned short*)carve((size_t)LAYERS * NRELS * HDIM * 2);
    float*          ab     = (float*)carve((size_t)NN * 8 * 4);
    float*          be     = (float*)carve((size_t)LAYERS * NRELS * NH * 4);
    int*            row_ptr= (int*)carve((size_t)(NN + 1) * 4);
    int*            counts = (int*)carve((size_t)NN * 4);
    int*            cursor = (int*)carve((size_t)NN * 4);
    int*            psums  = (int*)carve((size_t)NB * 4);
    int*            offs   = (int*)carve((size_t)NB * 4);
    unsigned*       pkq    = (unsigned*)carve((size_t)EE * 4);

    const int* dst = edge_idx + EE;

    // fused prep (hb, Wt, xeb, be, counts=0)
    prep_misc_kernel<<<PM_TOT, 256, 0, stream>>>(
        x_flat, Wl, Wr, rel_emb, We, att, hb, Wt, xeb, be, counts);

    // CSR build (parallel scan) + pkq
    count_kernel<<<(EE + 255) / 256, 256, 0, stream>>>(dst, counts);
    psum_kernel<<<NB, 256, 0, stream>>>(counts, psums);
    pscan_kernel<<<1, 256, 0, stream>>>(psums, offs, row_ptr);
    pfin_kernel<<<NB, 256, 0, stream>>>(counts, offs, row_ptr, cursor);
    scatter_pk_kernel<<<(EE + 255) / 256, 256, 0, stream>>>(edge_idx, edge_ty, cursor, pkq);

    const float* h_cur = x_flat;
    for (int l = 0; l < LAYERS; ++l) {
        float* h_next = (l == LAYERS - 1) ? (float*)d_out : h1;
        gemm_xlxr_ab_kernel<<<(NN + 31) / 32, 256, 0, stream>>>(
            hb,
            Wt + (size_t)(l * 2 + 0) * DM * HDIM,
            Wt + (size_t)(l * 2 + 1) * DM * HDIM,
            bl + (size_t)l * HDIM, br + (size_t)l * HDIM,
            att + (size_t)l * HDIM,
            xl, xr, ab);
        node_fused_kernel<<<NN / 4, 256, 0, stream>>>(
            row_ptr, pkq, xl, xr,
            xeb + (size_t)l * NRELS * HDIM,
            ab, be + (size_t)l * NRELS * NH,
            att + (size_t)l * HDIM,
            h_cur,
            b_out + (size_t)l * DM, ln_g + (size_t)l * DM, ln_b + (size_t)l * DM,
            h_next, hb);
        h_cur = h_next;
    }
}